// Round 6
// baseline (356.728 us; speedup 1.0000x reference)
//
#include <hip/hip_runtime.h>
#include <math.h>

// Problem constants
#define BATCH 4
#define C 256
#define H 128
#define W 128
#define HW (H * W)          // 16384
#define OH 256
#define OW 256
#define KSPLIT 8
#define KCH (C / KSPLIT)         // 32
#define SCH 16                   // channels per sample block (32KB tile)
#define NCHUNK (C / SCH)         // 16
__device__ __constant__ float OFF_FACTOR = 0.70710678118654752f; // sqrt(128/256)

typedef float __attribute__((ext_vector_type(2))) f32x2;

// ---------------------------------------------------------------------------
// Kernel A v2: fused 1x1 conv + descriptor compute (unchanged from R5).
// 1024 blocks (4/CU), KSPLIT=8, 2 pixels/thread via float2.
// ---------------------------------------------------------------------------
__global__ __launch_bounds__(256) void conv_desc_kernel(
    const float* __restrict__ x, const float* __restrict__ cw,
    const float* __restrict__ cb, float2* __restrict__ desc) {
    __shared__ float sw[8 * C];                              // 8 KB weights
    __shared__ __align__(16) float red[KSPLIT * 8 * 64];     // 16 KB partials
    int t = threadIdx.x;

    #pragma unroll
    for (int i = 0; i < 8; ++i) sw[i * 256 + t] = cw[i * 256 + t];
    __syncthreads();

    // ---- phase 1: partial conv ----
    int k = t >> 5;                   // ksplit chunk 0..7
    int q = t & 31;                   // float2-group within block, 0..31
    int g2 = blockIdx.x * 32 + q;     // global float2-group
    int g = g2 * 2;                   // first pixel
    int b = g >> 14;
    int pix = g & (HW - 1);
    const float* xp = x + (size_t)b * C * HW + (size_t)(k * KCH) * HW + pix;
    const float* swk = sw + k * KCH;

    f32x2 acc[8];
    #pragma unroll
    for (int o = 0; o < 8; ++o) acc[o] = (f32x2){0.f, 0.f};

    #pragma unroll 8
    for (int c = 0; c < KCH; ++c) {
        f32x2 v = *(const f32x2*)(xp + (size_t)c * HW);
        #pragma unroll
        for (int o = 0; o < 8; ++o) {
            float wv = swk[o * 256 + c];
            acc[o] += v * wv;
        }
    }

    #pragma unroll
    for (int o = 0; o < 8; ++o)
        *(f32x2*)&red[((k * 8 + o) << 6) + (q << 1)] = acc[o];
    __syncthreads();

    // ---- phase 2: thread = (sub-sample j, pixel p) ----
    int p = t & 63;
    int j = t >> 6;                   // 0..3 ; sx = j&1, sy = j>>1
    int gpix = blockIdx.x * 64 + p;
    int b2 = gpix >> 14;
    int pix2 = gpix & (HW - 1);
    int h2 = pix2 >> 7;
    int w2 = pix2 & (W - 1);

    float s_x = cb[j];
    float s_y = cb[4 + j];
    #pragma unroll
    for (int kk = 0; kk < KSPLIT; ++kk) {
        s_x += red[((kk * 8 + j) << 6) + p];
        s_y += red[((kk * 8 + 4 + j) << 6) + p];
    }

    int sx = j & 1, sy = j >> 1;
    float xc = OFF_FACTOR * s_x + (float)w2 + 0.5f * (float)sx;
    float yc = OFF_FACTOR * s_y + (float)h2 + 0.5f * (float)sy;
    int pout = (b2 * OH + 2 * h2 + sy) * OW + 2 * w2 + sx;
    desc[pout] = make_float2(xc, yc);
}

// ---------------------------------------------------------------------------
// Kernel B v3: bilinear gather through LDS, store-path restructured.
// Thread = (output row r = t>>6 of the block's 4 rows, col group q = t&63
// covering cols 4q..4q+3). Each thread: 4 sub-samples of ONE row ->
// ONE plain float4 store per channel (was 2x 8B nt stores). A/B vs R5:
// tests whether the nt hint / 8B store granularity was the residual cost.
// Gather, staging, decode unchanged.
// ---------------------------------------------------------------------------
__global__ __launch_bounds__(256) void sample_kernel(
    const float* __restrict__ x, const float4* __restrict__ desc4,
    float* __restrict__ out) {
    __shared__ __align__(16) float tile[SCH * 4 * W];   // [c][row][col], 32 KB
    int t = threadIdx.x;
    int lin = blockIdx.x;                 // 0..4095
    int xcd = lin & 7;
    int i8  = lin >> 3;                   // 0..511
    int combo = xcd * 8 + (i8 >> 6);      // 0..63 = (b, chunk)
    int hblk  = i8 & 63;
    int b = combo >> 4;
    int chunk = combo & 15;
    int h0 = hblk * 2;
    int c0 = chunk * SCH;

    const float* xb = x + (size_t)b * C * HW + (size_t)c0 * HW;

    // ---- stage rows clamp(h0-1 .. h0+2) x 16 ch, fully coalesced float4 ----
    #pragma unroll
    for (int j = 0; j < 8; ++j) {
        int idx = (j * 256 + t) * 4;      // float index in tile (16B aligned)
        int c   = idx >> 9;               // /512
        int i   = (idx >> 7) & 3;
        int col = idx & 127;
        int row = min(max(h0 - 1 + i, 0), H - 1);
        *(float4*)&tile[idx] =
            *(const float4*)(xb + (size_t)c * HW + row * W + col);
    }

    // ---- per-thread descriptor decode: 4 cols of one output row ----
    int r  = t >> 6;                      // 0..3: output row 2*h0 + r
    int q  = t & 63;                      // col group: cols 4q..4q+3
    int oh = 2 * h0 + r;

    // desc for (oh, 4q..4q+3): two float4 = 4 (xc,yc) pairs
    size_t dbase = (((size_t)b * OH + oh) * OW + 4 * q) >> 1;
    float4 d0 = desc4[dbase];
    float4 d1 = desc4[dbase + 1];

    int   loff[4];          // base tap: iy0*W + x0c (taps at +0,+1,+W,+W+1)
    float wt[4][4];
    bool allok = true;
    float xcs[4] = {d0.x, d0.z, d1.x, d1.z};
    float ycs[4] = {d0.y, d0.w, d1.y, d1.w};
    #pragma unroll
    for (int j = 0; j < 4; ++j) {
        float xc = xcs[j], yc = ycs[j];
        float x0f = floorf(xc), y0f = floorf(yc);
        int x0 = (int)x0f, y0 = (int)y0f;
        // fold clamp into weights: taps become x0c..x0c+1, y0c..y0c+1
        int x0c = min(max(x0, 0), W - 2);
        int y0c = min(max(y0, 0), H - 2);
        float fx = (x0 < 0) ? 0.f : ((x0 > W - 2) ? 1.f : xc - x0f);
        float fy = (y0 < 0) ? 0.f : ((y0 > H - 2) ? 1.f : yc - y0f);
        int iy0 = y0c - h0 + 1;                       // LDS row of top tap
        allok = allok && ((unsigned)iy0 <= 2u);       // rows iy0, iy0+1 in 0..3
        loff[j] = iy0 * W + x0c;
        wt[j][0] = (1.f - fx) * (1.f - fy); wt[j][1] = fx * (1.f - fy);
        wt[j][2] = (1.f - fx) * fy;         wt[j][3] = fx * fy;
    }

    __syncthreads();

    float* op0 = out + (((size_t)(b * C + c0) * OH + oh) * OW) + 4 * q;

    if (__all(allok)) {
        // ---- fast path: taps {b,b+1,b+W,b+W+1} -> ds_read2_b32 pairs ----
        #pragma unroll 4
        for (int c = 0; c < SCH; ++c) {
            const float* tl = tile + c * (4 * W);
            float v[4];
            #pragma unroll
            for (int j = 0; j < 4; ++j) {
                int bj = loff[j];
                float t00 = tl[bj],     t01 = tl[bj + 1];
                float t10 = tl[bj + W], t11 = tl[bj + W + 1];
                v[j] = t00 * wt[j][0] + t01 * wt[j][1] +
                       t10 * wt[j][2] + t11 * wt[j][3];
            }
            *(float4*)(op0 + (size_t)c * (OH * OW)) =
                make_float4(v[0], v[1], v[2], v[3]);
        }
    } else {
        // ---- exact fallback: gather straight from global x ----
        int rebase = (h0 - 1) * W;        // loff + rebase == y0c*W + x0c
        #pragma unroll 2
        for (int c = 0; c < SCH; ++c) {
            const float* pl = xb + (size_t)c * HW;
            float v[4];
            #pragma unroll
            for (int j = 0; j < 4; ++j) {
                int bj = loff[j] + rebase;
                v[j] = pl[bj]         * wt[j][0] + pl[bj + 1]     * wt[j][1] +
                       pl[bj + W]     * wt[j][2] + pl[bj + W + 1] * wt[j][3];
            }
            *(float4*)(op0 + (size_t)c * (OH * OW)) =
                make_float4(v[0], v[1], v[2], v[3]);
        }
    }
}

extern "C" void kernel_launch(void* const* d_in, const int* in_sizes, int n_in,
                              void* d_out, int out_size, void* d_ws, size_t ws_size,
                              hipStream_t stream) {
    const float* x  = (const float*)d_in[0];
    const float* cw = (const float*)d_in[1];
    const float* cb = (const float*)d_in[2];
    float* out = (float*)d_out;

    float2* desc = (float2*)d_ws;   // 2.1 MB

    conv_desc_kernel<<<1024, 256, 0, stream>>>(x, cw, cb, desc);
    sample_kernel<<<BATCH * (H / 2) * NCHUNK, 256, 0, stream>>>(
        x, (const float4*)desc, out);
}

// Round 7
// 313.342 us; speedup vs baseline: 1.1385x; 1.1385x over previous
//
#include <hip/hip_runtime.h>
#include <math.h>

// Problem constants
#define BATCH 4
#define C 256
#define H 128
#define W 128
#define HW (H * W)          // 16384
#define OH 256
#define OW 256
#define KSPLIT 8
#define KCH (C / KSPLIT)         // 32
#define SCH 16                   // channels per sample block (32KB tile)
#define NCHUNK (C / SCH)         // 16
__device__ __constant__ float OFF_FACTOR = 0.70710678118654752f; // sqrt(128/256)

typedef float __attribute__((ext_vector_type(2))) f32x2;
typedef float __attribute__((ext_vector_type(4))) f32x4;  // nt-store-compatible

// ---------------------------------------------------------------------------
// Kernel A v2: fused 1x1 conv + descriptor compute (unchanged from R5).
// 1024 blocks (4/CU), KSPLIT=8, 2 pixels/thread via float2.
// ---------------------------------------------------------------------------
__global__ __launch_bounds__(256) void conv_desc_kernel(
    const float* __restrict__ x, const float* __restrict__ cw,
    const float* __restrict__ cb, float2* __restrict__ desc) {
    __shared__ float sw[8 * C];                              // 8 KB weights
    __shared__ __align__(16) float red[KSPLIT * 8 * 64];     // 16 KB partials
    int t = threadIdx.x;

    #pragma unroll
    for (int i = 0; i < 8; ++i) sw[i * 256 + t] = cw[i * 256 + t];
    __syncthreads();

    // ---- phase 1: partial conv ----
    int k = t >> 5;                   // ksplit chunk 0..7
    int q = t & 31;                   // float2-group within block, 0..31
    int g2 = blockIdx.x * 32 + q;     // global float2-group
    int g = g2 * 2;                   // first pixel
    int b = g >> 14;
    int pix = g & (HW - 1);
    const float* xp = x + (size_t)b * C * HW + (size_t)(k * KCH) * HW + pix;
    const float* swk = sw + k * KCH;

    f32x2 acc[8];
    #pragma unroll
    for (int o = 0; o < 8; ++o) acc[o] = (f32x2){0.f, 0.f};

    #pragma unroll 8
    for (int c = 0; c < KCH; ++c) {
        f32x2 v = *(const f32x2*)(xp + (size_t)c * HW);
        #pragma unroll
        for (int o = 0; o < 8; ++o) {
            float wv = swk[o * 256 + c];
            acc[o] += v * wv;
        }
    }

    #pragma unroll
    for (int o = 0; o < 8; ++o)
        *(f32x2*)&red[((k * 8 + o) << 6) + (q << 1)] = acc[o];
    __syncthreads();

    // ---- phase 2: thread = (sub-sample j, pixel p) ----
    int p = t & 63;
    int j = t >> 6;                   // 0..3 ; sx = j&1, sy = j>>1
    int gpix = blockIdx.x * 64 + p;
    int b2 = gpix >> 14;
    int pix2 = gpix & (HW - 1);
    int h2 = pix2 >> 7;
    int w2 = pix2 & (W - 1);

    float s_x = cb[j];
    float s_y = cb[4 + j];
    #pragma unroll
    for (int kk = 0; kk < KSPLIT; ++kk) {
        s_x += red[((kk * 8 + j) << 6) + p];
        s_y += red[((kk * 8 + 4 + j) << 6) + p];
    }

    int sx = j & 1, sy = j >> 1;
    float xc = OFF_FACTOR * s_x + (float)w2 + 0.5f * (float)sx;
    float yc = OFF_FACTOR * s_y + (float)h2 + 0.5f * (float)sy;
    int pout = (b2 * OH + 2 * h2 + sy) * OW + 2 * w2 + sx;
    desc[pout] = make_float2(xc, yc);
}

// ---------------------------------------------------------------------------
// Kernel B v4: bilinear gather through LDS.
// R6's row-mapped structure (thread = output row r=t>>6, col group q=t&63,
// ONE float4 store per channel) but with the NONTEMPORAL hint restored.
// R6 A/B showed plain stores cost +43us (268MB stream thrashes L2/L3 and
// evicts the x slabs other blocks re-stage); this isolates store WIDTH
// with the hint held fixed. Gather taps x0c~2q -> 16 even banks -> 2-way
// aliasing (free, m136).
// ---------------------------------------------------------------------------
__global__ __launch_bounds__(256) void sample_kernel(
    const float* __restrict__ x, const float4* __restrict__ desc4,
    float* __restrict__ out) {
    __shared__ __align__(16) float tile[SCH * 4 * W];   // [c][row][col], 32 KB
    int t = threadIdx.x;
    int lin = blockIdx.x;                 // 0..4095
    int xcd = lin & 7;
    int i8  = lin >> 3;                   // 0..511
    int combo = xcd * 8 + (i8 >> 6);      // 0..63 = (b, chunk)
    int hblk  = i8 & 63;
    int b = combo >> 4;
    int chunk = combo & 15;
    int h0 = hblk * 2;
    int c0 = chunk * SCH;

    const float* xb = x + (size_t)b * C * HW + (size_t)c0 * HW;

    // ---- stage rows clamp(h0-1 .. h0+2) x 16 ch, fully coalesced float4 ----
    #pragma unroll
    for (int j = 0; j < 8; ++j) {
        int idx = (j * 256 + t) * 4;      // float index in tile (16B aligned)
        int c   = idx >> 9;               // /512
        int i   = (idx >> 7) & 3;
        int col = idx & 127;
        int row = min(max(h0 - 1 + i, 0), H - 1);
        *(float4*)&tile[idx] =
            *(const float4*)(xb + (size_t)c * HW + row * W + col);
    }

    // ---- per-thread descriptor decode: 4 cols of one output row ----
    int r  = t >> 6;                      // 0..3: output row 2*h0 + r
    int q  = t & 63;                      // col group: cols 4q..4q+3
    int oh = 2 * h0 + r;

    // desc for (oh, 4q..4q+3): two float4 = 4 (xc,yc) pairs
    size_t dbase = (((size_t)b * OH + oh) * OW + 4 * q) >> 1;
    float4 d0 = desc4[dbase];
    float4 d1 = desc4[dbase + 1];

    int   loff[4];          // base tap: iy0*W + x0c (taps at +0,+1,+W,+W+1)
    float wt[4][4];
    bool allok = true;
    float xcs[4] = {d0.x, d0.z, d1.x, d1.z};
    float ycs[4] = {d0.y, d0.w, d1.y, d1.w};
    #pragma unroll
    for (int j = 0; j < 4; ++j) {
        float xc = xcs[j], yc = ycs[j];
        float x0f = floorf(xc), y0f = floorf(yc);
        int x0 = (int)x0f, y0 = (int)y0f;
        // fold clamp into weights: taps become x0c..x0c+1, y0c..y0c+1
        int x0c = min(max(x0, 0), W - 2);
        int y0c = min(max(y0, 0), H - 2);
        float fx = (x0 < 0) ? 0.f : ((x0 > W - 2) ? 1.f : xc - x0f);
        float fy = (y0 < 0) ? 0.f : ((y0 > H - 2) ? 1.f : yc - y0f);
        int iy0 = y0c - h0 + 1;                       // LDS row of top tap
        allok = allok && ((unsigned)iy0 <= 2u);       // rows iy0, iy0+1 in 0..3
        loff[j] = iy0 * W + x0c;
        wt[j][0] = (1.f - fx) * (1.f - fy); wt[j][1] = fx * (1.f - fy);
        wt[j][2] = (1.f - fx) * fy;         wt[j][3] = fx * fy;
    }

    __syncthreads();

    float* op0 = out + (((size_t)(b * C + c0) * OH + oh) * OW) + 4 * q;

    if (__all(allok)) {
        // ---- fast path: taps {b,b+1,b+W,b+W+1} -> ds_read2_b32 pairs ----
        #pragma unroll 4
        for (int c = 0; c < SCH; ++c) {
            const float* tl = tile + c * (4 * W);
            float v[4];
            #pragma unroll
            for (int j = 0; j < 4; ++j) {
                int bj = loff[j];
                float t00 = tl[bj],     t01 = tl[bj + 1];
                float t10 = tl[bj + W], t11 = tl[bj + W + 1];
                v[j] = t00 * wt[j][0] + t01 * wt[j][1] +
                       t10 * wt[j][2] + t11 * wt[j][3];
            }
            f32x4 rv = {v[0], v[1], v[2], v[3]};
            __builtin_nontemporal_store(rv,
                (f32x4*)(op0 + (size_t)c * (OH * OW)));
        }
    } else {
        // ---- exact fallback: gather straight from global x ----
        int rebase = (h0 - 1) * W;        // loff + rebase == y0c*W + x0c
        #pragma unroll 2
        for (int c = 0; c < SCH; ++c) {
            const float* pl = xb + (size_t)c * HW;
            float v[4];
            #pragma unroll
            for (int j = 0; j < 4; ++j) {
                int bj = loff[j] + rebase;
                v[j] = pl[bj]         * wt[j][0] + pl[bj + 1]     * wt[j][1] +
                       pl[bj + W]     * wt[j][2] + pl[bj + W + 1] * wt[j][3];
            }
            f32x4 rv = {v[0], v[1], v[2], v[3]};
            __builtin_nontemporal_store(rv,
                (f32x4*)(op0 + (size_t)c * (OH * OW)));
        }
    }
}

extern "C" void kernel_launch(void* const* d_in, const int* in_sizes, int n_in,
                              void* d_out, int out_size, void* d_ws, size_t ws_size,
                              hipStream_t stream) {
    const float* x  = (const float*)d_in[0];
    const float* cw = (const float*)d_in[1];
    const float* cb = (const float*)d_in[2];
    float* out = (float*)d_out;

    float2* desc = (float2*)d_ws;   // 2.1 MB

    conv_desc_kernel<<<1024, 256, 0, stream>>>(x, cw, cb, desc);
    sample_kernel<<<BATCH * (H / 2) * NCHUNK, 256, 0, stream>>>(
        x, (const float4*)desc, out);
}